// Round 5
// baseline (27.162 us; speedup 1.0000x reference)
//
#include <hip/hip_runtime.h>
#include <math.h>

// EdgeConstructor: out[b][i][j] = { dR(i,j), mass(i,j) } for B=256, N=256.
// v5: v4 + LDS packed as two float4 arrays -> 2x ds_read_b128 per row-iter
// (was 7x ds_read_b32; LDS pipe was co-critical with the store pipe).

#define BATCH 256
#define NN 256
#define TI 32  // rows per block

typedef float f4 __attribute__((ext_vector_type(4)));

__global__ __launch_bounds__(256)
void edge_kernel(const float* __restrict__ x, float* __restrict__ out) {
    const int b   = blockIdx.y;
    const int i0  = blockIdx.x * TI;
    const int tid = threadIdx.x;

    __shared__ f4 s_a[NN];  // {eta, phi, E, m2}
    __shared__ f4 s_b[NN];  // {px, py, pz, 0}

    const float TWO_PI     = 6.28318530717958647692f;
    const float INV_TWO_PI = 0.15915494309189533577f;

    // Phase 1: each thread precomputes node `tid` of batch b.
    const float4 v = reinterpret_cast<const float4*>(x)[b * NN + tid];
    const float pt  = v.x;
    const float eta = v.y;
    const float phi = v.z;
    const float E   = v.w;

    // phi, eta in [0,1): fast HW transcendentals, no range reduction needed.
    const float sp = __sinf(phi);
    const float cp = __cosf(phi);
    const float ex = __expf(eta);
    const float px = pt * cp;
    const float py = pt * sp;
    const float pz = pt * 0.5f * (ex - __builtin_amdgcn_rcpf(ex)); // sinh(eta)
    const float p2  = fmaf(px, px, fmaf(py, py, pz * pz));
    const float m2n = fmaf(E, E, -p2);   // node invariant mass^2

    {
        f4 a; a.x = eta; a.y = phi; a.z = E;  a.w = m2n;
        f4 bb; bb.x = px; bb.y = py; bb.z = pz; bb.w = 0.0f;
        s_a[tid] = a;
        s_b[tid] = bb;
    }
    __syncthreads();

    // Phase 2: thread = column j = tid; loop over TI rows.
    float2* outp = reinterpret_cast<float2*>(out)
                 + ((size_t)b * NN + (size_t)i0) * NN + tid;

#pragma unroll 8
    for (int r = 0; r < TI; ++r) {
        const int i = i0 + r;
        // row-i values: wave-uniform LDS broadcast, 2x ds_read_b128
        const f4 a  = s_a[i];
        const f4 bb = s_b[i];

        const float deta = a.x - eta;
        float d = a.y - phi;
        // jnp.mod(d + pi, 2pi) - pi  ==  d - 2pi*floor(d/2pi + 0.5)
        const float f = floorf(fmaf(d, INV_TWO_PI, 0.5f));
        d = fmaf(-TWO_PI, f, d);
        const float r2 = fmaxf(fmaf(deta, deta, d * d), 1e-12f);
        const float dR = __builtin_amdgcn_sqrtf(r2);

        // m^2(i,j) = m2_i + m2_j + 2*(E_i E_j - p_i . p_j)
        float c = a.z * E;
        c = fmaf(-bb.x, px, c);
        c = fmaf(-bb.y, py, c);
        c = fmaf(-bb.z, pz, c);
        const float m2 = fmaf(2.0f, c, a.w + m2n);
        const float mass = __builtin_amdgcn_sqrtf(fmaxf(m2, 1e-12f));

        outp[(size_t)r * NN] = make_float2(dR, mass);
    }
}

extern "C" void kernel_launch(void* const* d_in, const int* in_sizes, int n_in,
                              void* d_out, int out_size, void* d_ws, size_t ws_size,
                              hipStream_t stream) {
    const float* x = (const float*)d_in[0];
    float* out = (float*)d_out;
    dim3 grid(NN / TI, BATCH);
    dim3 block(256);
    edge_kernel<<<grid, block, 0, stream>>>(x, out);
}